// Round 1
// 429.416 us; speedup vs baseline: 1.0236x; 1.0236x over previous
//
#include <hip/hip_runtime.h>

#define NLVL 16
#define NTOT 1846083
#define NBLK 4376

typedef float  f32x4  __attribute__((ext_vector_type(4)));
typedef __bf16 bf16x8 __attribute__((ext_vector_type(8)));
typedef __bf16 bf16x4 __attribute__((ext_vector_type(4)));
typedef unsigned int u32x4 __attribute__((ext_vector_type(4)));

// level tables (static in reference)
__constant__ int c_R[NLVL]   = {16,18,20,22,25,27,30,34,38,42,47,52,58,64,72,80};
__constant__ int c_off[NLVL] = {0,4096,9928,17928,28576,44201,63884,90884,130188,185060,259148,362971,503579,698691,960835,1334083};
__constant__ int c_czy[NLVL] = {4,5,5,6,7,7,8,9,10,11,12,13,15,16,18,20};   // ceil(R/4)
__constant__ int c_cx[NLVL]  = {1,2,2,2,2,2,2,3,3,3,3,4,4,4,5,5};           // ceil(R/16) (= z-chunks too)
// blocks ordered level 15 -> 0 (longest first); count[l] = 2*czy*cx*cx
__constant__ int c_base[17]  = {0,1000,1900,2412,2892,3308,3524,3722,3902,4064,4128,4184,4240,4288,4328,4368,4376};

// B fragments: [level][kz(3)][pair(5)][lane(64)][8 bf16] = 240 KB
__device__ __align__(16) unsigned short g_bfrag[NLVL*3*5*64*8];

// ---------------------------------------------------------------------------
// Pack weights into MFMA B fragments. B[k][n]: n=lane&15, k=(lane>>4)*8+j.
// k -> tap_in_pair = k>>4, ci = k&15; in-plane tap t2 = 2*pair + tip (9 taps,
// t2==9 padded with zero).
// ---------------------------------------------------------------------------
__global__ void prep_bfrag(const float* __restrict__ wgt) {
    int tid = blockIdx.x * 256 + threadIdx.x;
    if (tid >= NLVL*3*5*64) return;
    int lane = tid & 63;
    int p    = (tid >> 6) % 5;
    int d    = (tid / (5*64)) % 3;
    int l    = tid / (3*5*64);
    int quad = lane >> 4, co = lane & 15;
    unsigned short v[8];
#pragma unroll
    for (int j = 0; j < 8; ++j) {
        int k   = quad*8 + j;
        int tip = k >> 4;
        int ci  = k & 15;
        int t2  = 2*p + tip;
        float f = (t2 < 9) ? wgt[((l*27 + d*9 + t2)*16 + ci)*16 + co] : 0.f;
        v[j] = __builtin_bit_cast(unsigned short, (__bf16)f);
    }
    u32x4 pk;
    pk[0] = (unsigned)v[0] | ((unsigned)v[1] << 16);
    pk[1] = (unsigned)v[2] | ((unsigned)v[3] << 16);
    pk[2] = (unsigned)v[4] | ((unsigned)v[5] << 16);
    pk[3] = (unsigned)v[6] | ((unsigned)v[7] << 16);
    *(u32x4*)&g_bfrag[(size_t)tid*8] = pk;
}

// ---------------------------------------------------------------------------
// Streaming-z conv: block = 4 waves, tile 16x * 4y, z-chunk of 16.
// Pipeline (2-deep): loads for plane z+2 issued at step i (parked in VGPRs
// across the barrier), LDS-written at step i+1, consumed at step i+2.
// Raw s_barrier + manual lgkmcnt(0) so prefetch loads stay in flight.
// MFMA operands swapped (weights as A) so C is [co][x]: one dwordx4 store/lane.
// ---------------------------------------------------------------------------
__global__ __launch_bounds__(256, 3)
void conv_kernel(const float* __restrict__ in,
                 const float* __restrict__ bias,
                 float* __restrict__ out) {
    // two planes: [yp 0..5][xp 0..17][ci 0..15] bf16 = 3456 B each
    __shared__ __align__(16) __bf16 slab[2*1728];

    const int bid = blockIdx.x;
    int idx = 0;
#pragma unroll
    for (int i = 1; i < 16; ++i) if (bid >= c_base[i]) idx = i;
    const int l = 15 - idx;
    const int R = c_R[l], off = c_off[l], czy = c_czy[l], cx = c_cx[l];

    int local = bid - c_base[idx];
    int per_b = czy*cx*cx;
    int bb = local / per_b;         int r1 = local - bb*per_b;
    int zt = r1 / (czy*cx);         int r2 = r1 - zt*(czy*cx);
    int yt = r2 / cx;               int xt = r2 - yt*cx;
    const int z0 = zt*16;
    const int z1 = (z0 + 16 < R) ? z0 + 16 : R;
    const int y0 = yt*4, x0 = xt*16;

    // ---- per-lane constants ----
    const int t    = threadIdx.x;
    const int lane = t & 63;
    const int wv   = t >> 6;
    const int quad = lane >> 4;
    const int m    = lane & 15;
    const int qh   = quad >> 1;

    // ---- B fragments resident (15 x 16B per lane) ----
    bf16x8 bfr[15];
#pragma unroll
    for (int d = 0; d < 3; ++d)
#pragma unroll
        for (int p = 0; p < 5; ++p)
            bfr[d*5+p] = *(const bf16x8*)&g_bfrag[(size_t)(((l*3 + d)*5 + p)*64 + lane)*8];

    // ---- A-frag byte offsets within a plane (5 pairs) ----
    const int albase = wv*576 + m*32 + (quad & 1)*16;
    int aoff[5];
    {
        const int T0[5] = {0, 64, 608, 1152, 1216};
        const int T1[5] = {32, 576, 640, 1184, 1216};
#pragma unroll
        for (int p = 0; p < 5; ++p) aoff[p] = albase + (qh ? T1[p] : T0[p]);
    }

    // ---- staging precompute: plane = 432 float4; thread does c and c+256 ----
    const long zs = (long)R*R*16;
    long g0 = 0, g1 = 0; int lo0 = 0, lo1 = 0; bool yx0 = false, yx1 = false;
    {
        int c = t;
        int yp = c/72; int rem = c - yp*72; int xp = rem>>2; int ci4 = (rem&3)<<2;
        lo0 = (yp*18 + xp)*16 + ci4;
        int y = y0 + yp - 1, x = x0 + xp - 1;
        yx0 = ((unsigned)y < (unsigned)R) && ((unsigned)x < (unsigned)R);
        g0 = ((long)bb*NTOT + off)*16 + ((long)y*R + x)*16 + ci4;
    }
    const bool has1 = (t < 176);
    if (has1) {
        int c = t + 256;
        int yp = c/72; int rem = c - yp*72; int xp = rem>>2; int ci4 = (rem&3)<<2;
        lo1 = (yp*18 + xp)*16 + ci4;
        int y = y0 + yp - 1, x = x0 + xp - 1;
        yx1 = ((unsigned)y < (unsigned)R) && ((unsigned)x < (unsigned)R);
        g1 = ((long)bb*NTOT + off)*16 + ((long)y*R + x)*16 + ci4;
    }

    __bf16* sbr = slab;          // plane being read
    __bf16* sbw = slab + 1728;   // plane being written

    const f32x4 zero4 = {0,0,0,0};
    f32x4 rA0 = zero4, rA1 = zero4, rB0 = zero4, rB1 = zero4;

    // ---- prologue: issue loads for planes z0-1 (rA) and z0 (rB);
    //      stage z0-1 into sbr; keep z0 in registers across the barrier ----
    {
        int zn = z0 - 1;
        if (zn >= 0) {
            if (yx0) rA0 = *(const f32x4*)(in + g0 + (long)zn*zs);
            if (has1 && yx1) rA1 = *(const f32x4*)(in + g1 + (long)zn*zs);
        }
        if (yx0) rB0 = *(const f32x4*)(in + g0 + (long)z0*zs);
        if (has1 && yx1) rB1 = *(const f32x4*)(in + g1 + (long)z0*zs);
        bf16x4 h0 = {(__bf16)rA0[0],(__bf16)rA0[1],(__bf16)rA0[2],(__bf16)rA0[3]};
        *(bf16x4*)(sbr + lo0) = h0;
        if (has1) {
            bf16x4 h1 = {(__bf16)rA1[0],(__bf16)rA1[1],(__bf16)rA1[2],(__bf16)rA1[3]};
            *(bf16x4*)(sbr + lo1) = h1;
        }
    }
    asm volatile("s_waitcnt lgkmcnt(0)" ::: "memory");
    __builtin_amdgcn_s_barrier();
    asm volatile("" ::: "memory");

    const bool ywok = (y0 + wv) < R;
    const f32x4 bv4 = *(const f32x4*)(bias + (l << 4) + (quad << 2));
    const long obase = ((long)bb*NTOT + off)*16;
    const int steps = z1 - z0 + 2;

    f32x4 accA = zero4, accB = zero4, accC = zero4;

    auto stepf = [&](int i, f32x4& w0, f32x4& w1, f32x4& l0, f32x4& l1) {
        // 1) issue loads for plane z0+1+i (LDS-written at step i+1)
        const int zl = z0 + 1 + i;
        if (zl <= z1) {
            const bool zok = zl < R;
            l0 = zero4; l1 = zero4;
            if (zok && yx0) l0 = *(const f32x4*)(in + g0 + (long)zl*zs);
            if (has1 && zok && yx1) l1 = *(const f32x4*)(in + g1 + (long)zl*zs);
        }
        // 2) stage plane z0+i (loaded one full step ago) into sbw
        if (i <= steps - 2) {
            bf16x4 h0 = {(__bf16)w0[0],(__bf16)w0[1],(__bf16)w0[2],(__bf16)w0[3]};
            *(bf16x4*)(sbw + lo0) = h0;
            if (has1) {
                bf16x4 h1 = {(__bf16)w1[0],(__bf16)w1[1],(__bf16)w1[2],(__bf16)w1[3]};
                *(bf16x4*)(sbw + lo1) = h1;
            }
        }
        // 3) compute plane zp = z0-1+i from sbr (weights as A -> C[co][x])
        const char* sb = (const char*)sbr;
#pragma unroll
        for (int p = 0; p < 5; ++p) {
            bf16x8 a = *(const bf16x8*)(sb + aoff[p]);
            accC = __builtin_amdgcn_mfma_f32_16x16x32_bf16(bfr[p],    a, accC, 0, 0, 0); // kz=0 -> out zp+1
            accB = __builtin_amdgcn_mfma_f32_16x16x32_bf16(bfr[5+p],  a, accB, 0, 0, 0); // kz=1 -> out zp
            accA = __builtin_amdgcn_mfma_f32_16x16x32_bf16(bfr[10+p], a, accA, 0, 0, 0); // kz=2 -> out zp-1
        }
        // 4) output plane z0-2+i completed (accA): one dwordx4 per lane
        if (i >= 2 && ywok) {
            const int x = x0 + m;
            if (x < R) {
                const int z = z0 - 2 + i;
                long rb = obase + (((long)z*R + (y0 + wv))*(long)R + x)*16 + (quad << 2);
                f32x4 o = accA + bv4;
                *(f32x4*)(out + rb) = o;
            }
        }
        // rotate accumulators
        accA = accB; accB = accC; accC = zero4;
        // barrier: LDS drained, prefetch loads stay in flight
        asm volatile("s_waitcnt lgkmcnt(0)" ::: "memory");
        __builtin_amdgcn_s_barrier();
        asm volatile("" ::: "memory");
        __bf16* t_ = sbr; sbr = sbw; sbw = t_;
    };

    int i = 0;
    for (; i + 1 < steps; i += 2) {
        stepf(i,     rB0, rB1, rA0, rA1);
        stepf(i + 1, rA0, rA1, rB0, rB1);
    }
    if (i < steps) stepf(i, rB0, rB1, rA0, rA1);
}

extern "C" void kernel_launch(void* const* d_in, const int* in_sizes, int n_in,
                              void* d_out, int out_size, void* d_ws, size_t ws_size,
                              hipStream_t stream) {
    const float* inp = (const float*)d_in[0];
    const float* wgt = (const float*)d_in[1];
    const float* bia = (const float*)d_in[2];
    float* out = (float*)d_out;
    prep_bfrag<<<dim3((NLVL*3*5*64 + 255)/256), dim3(256), 0, stream>>>(wgt);
    conv_kernel<<<dim3(NBLK), dim3(256), 0, stream>>>(inp, bia, out);
}